// Round 13
// baseline (118.794 us; speedup 1.0000x reference)
//
#include <hip/hip_runtime.h>
#include <hip/hip_bf16.h>

#define NB    2048
#define NUMK  128
#define NE    1024
#define HID   32
#define ROWLEN (NUMK + NE + 2)
#define CAP   24                 // padded slots per row (unique srcs + self)
#define NPS   (NUMK * CAP)       // 3072
#define ASTRIDE 136              // bf16 elems per Â row (128 + 8 pad)
#define W2STRIDE 40              // bf16 elems per a1/W2T row (32 + 8 pad)
#define WSELF 1024               // widx of self-loop weight (1.0)
#define WPAD  1025               // widx of pad weight (0.0)
#define WVBASE 1026              // first vslot (chained dup merges)
#define MAXV  16
#define WTOT  (WVBASE + MAXV)    // 1042

// slot encoding: src(7) | widx(11)<<7 | widx2(11)<<18 | prim(1)<<29
// pslot layout (coalesced, 4 lanes/row x 6 slots):
//   pslot_g[e*512 + row*4 + l4] = psl[row][l4*6 + e],  e in [0,6)
// Pipeline: csr (1 blk) -> prep A (2048 blks: norms fp32 -> nvg, x1^T bf16 ->
// x1tg) -> main B (2048 blks: dense A^ MFMA chain, ONE barrier).

using s8  = __attribute__((ext_vector_type(8))) short;   // 8 bf16 = 16 B
using f4  = __attribute__((ext_vector_type(4))) float;
using fl4 = __attribute__((ext_vector_type(4))) float;

static __device__ __forceinline__ unsigned short f2bf(float f) {
    unsigned u = __float_as_uint(f);
    unsigned r = (u + 0x7fffu + ((u >> 16) & 1u)) >> 16;   // RNE
    return (unsigned short)r;
}

// ---------------------------------------------------------------------------
// Setup (once): CSR by dst, per-row dedup into (widx, widx2 [, vslot chain]);
// pre-pack W2^T bf16 B-frag layout into ws. (Validated R12 code.)
// ---------------------------------------------------------------------------
__global__ __launch_bounds__(1024) void build_csr_kernel(
    const int* __restrict__ ei,
    const float* __restrict__ W2,
    unsigned* __restrict__ pslot_g,    // [NPS]
    short* __restrict__ w2tg,          // [HID * W2STRIDE]
    unsigned* __restrict__ vmeta_g)    // [1 + MAXV]
{
    __shared__ unsigned cnt[NUMK], roff[NUMK + 1], cur[NUMK], incl[NUMK];
    __shared__ unsigned pk[NE];
    __shared__ unsigned psl[NUMK][CAP];
    __shared__ unsigned vc;
    const int t = threadIdx.x;

    if (t < NUMK) cnt[t] = 0u;
    if (t == 0) vc = 0u;
    {   // W2^T bf16 pack: w2tg[n*40+k] = bf16(W2[k*32+n])
        const int k = t >> 5, n = t & 31;
        w2tg[n * W2STRIDE + k] = (short)f2bf(W2[t]);
    }
    __syncthreads();
    const int dst = ei[NE + t] & (NUMK - 1);
    atomicAdd(&cnt[dst], 1u);
    __syncthreads();

    if (t < NUMK) {                              // exclusive scan (2 wave scans)
        unsigned v = cnt[t];
        #pragma unroll
        for (int d = 1; d < 64; d <<= 1) {
            unsigned u = __shfl_up(v, d, 64);
            if ((t & 63) >= d) v += u;
        }
        incl[t] = v;
    }
    __syncthreads();
    if (t < NUMK) {
        const unsigned base = (t >= 64) ? incl[63] : 0u;
        const unsigned off  = base + incl[t] - cnt[t];
        roff[t] = off; cur[t] = off;
    }
    if (t == 0) roff[NUMK] = (unsigned)NE;
    __syncthreads();

    {
        const int src = ei[t] & (NUMK - 1);
        const unsigned pos = atomicAdd(&cur[dst], 1u);
        pk[pos] = (unsigned)src | ((unsigned)t << 16);
    }
    __syncthreads();

    if (t < NUMK) {
        int np = 0;
        auto addOrMerge = [&](unsigned s, unsigned eid) {
            int j = -1;
            for (int i = 0; i < np; ++i)
                if ((psl[t][i] & 127u) == s) { j = i; break; }
            if (j >= 0) {
                const unsigned slot = psl[t][j];
                const unsigned w2x = (slot >> 18) & 0x7FFu;
                if (w2x == (unsigned)WPAD) {
                    psl[t][j] = (slot & ~(0x7FFu << 18)) | (eid << 18);
                } else {
                    const unsigned v = atomicAdd(&vc, 1u);
                    if (v < (unsigned)MAXV) {
                        vmeta_g[1 + v] = w2x | (eid << 11);
                        psl[t][j] = (slot & ~(0x7FFu << 18))
                                  | (((unsigned)WVBASE + v) << 18);
                    }
                }
            } else if (np < CAP) {
                psl[t][np++] = s | (eid << 7)
                             | ((unsigned)WPAD << 18) | (1u << 29);
            }
        };
        const unsigned k0 = roff[t], k1 = roff[t + 1];
        for (unsigned k = k0; k < k1; ++k)
            addOrMerge(pk[k] & 127u, pk[k] >> 16);
        addOrMerge((unsigned)t, (unsigned)WSELF);        // self-loop, w = 1
        for (int i = np; i < CAP; ++i)                   // pads: w = 0, prim = 0
            psl[t][i] = ((unsigned)WPAD << 7) | ((unsigned)WPAD << 18);
    }
    __syncthreads();

    for (int i = t; i < NPS; i += 1024) {
        const int e = i >> 9, rem = i & 511;
        const int r = rem >> 2, l4i = rem & 3;
        pslot_g[i] = psl[r][l4i * 6 + e];
    }
    if (t == 0) vmeta_g[0] = (vc <= (unsigned)MAXV) ? vc : (unsigned)MAXV;
}

// ---------------------------------------------------------------------------
// Prep kernel A: all sparse phases for one graph per block (512 thr).
// LDS ~5.7 KB -> latency well hidden; blocks retire fast. Outputs:
//   nvg[g*3072 + e*512 + tid]  fp32 norm per slot (coalesced)
//   x1tg[g*4096 + j*128 + k]   bf16 x1^T (B-frag-ready, 256 B rows)
// Numeric path identical to R11/R12 (same fp32 math, same RNE points).
// ---------------------------------------------------------------------------
__global__ __launch_bounds__(512, 6) void gcn_prep_kernel(
    const float* __restrict__ Hx,
    const float* __restrict__ W1, const float* __restrict__ b1,
    const unsigned* __restrict__ pslot_g,
    const unsigned* __restrict__ vmeta_g,
    float* __restrict__ nvg,
    short* __restrict__ x1tg)
{
    __shared__ __align__(16) float wshp[WTOT];          // 4168 B
    __shared__ float degv[NUMK], pbuf[NUMK], a0s[NUMK]; // 1536 B

    const int tid = threadIdx.x;                // 0..511
    const int row = tid >> 2, l4 = tid & 3;     // 128 rows x 4 lanes
    const float* rowp = Hx + (size_t)blockIdx.x * ROWLEN;

    unsigned su[6];
    #pragma unroll
    for (int e = 0; e < 6; ++e) su[e] = pslot_g[(e << 9) + tid];
    const unsigned vcnt = vmeta_g[0];

    // ---- stage weights/signals; vslot chains via GLOBAL reads (tid 0) ----
    *(float2*)&wshp[tid * 2] = *(const float2*)&rowp[NUMK + tid * 2];
    if (tid == 511) { wshp[WSELF] = 1.0f; wshp[WPAD] = 0.0f; }
    if (tid < NUMK) pbuf[tid] = rowp[tid];
    if (tid == 0 && vcnt) {
        for (unsigned v = 0; v < vcnt; ++v) {
            const unsigned e = vmeta_g[1 + v];
            const unsigned a = e & 0x7FFu, b = (e >> 11) & 0x7FFu;
            const float wa = (a < 1024u) ? rowp[NUMK + a]
                           : (a == (unsigned)WSELF ? 1.0f : wshp[a]);
            const float wb = (b < 1024u) ? rowp[NUMK + b]
                           : (b == (unsigned)WSELF ? 1.0f : wshp[b]);
            wshp[WVBASE + v] = wa + wb;
        }
    }
    __syncthreads();                                   // B1

    // ---- P2: merged slot weights + deg -> dinv ----
    float nvr[6];
    {
        float d = 0.f;
        #pragma unroll
        for (int e = 0; e < 6; ++e) {
            const unsigned u = su[e];
            nvr[e] = wshp[(u >> 7) & 0x7FFu] + wshp[(u >> 18) & 0x7FFu];
            d += nvr[e];
        }
        d += __shfl_xor(d, 1, 4);
        d += __shfl_xor(d, 2, 4);
        if (l4 == 0) degv[row] = rsqrtf(d);            // deg >= 1 (self w=1)
    }
    __syncthreads();                                   // B2

    // ---- P4: norms -> nvg (coalesced global) + a0 = A^·p ----
    {
        const float dr = degv[row];
        float acc = 0.f;
        float* nvp = nvg + (size_t)blockIdx.x * NPS;
        #pragma unroll
        for (int e = 0; e < 6; ++e) {
            const unsigned u = su[e];
            const int s = (int)(u & 127u);
            const float nv = (u >> 29) ? dr * degv[s] * nvr[e] : 0.f;
            nvp[(e << 9) + tid] = nv;
            acc = fmaf(nv, pbuf[s], acc);
        }
        acc += __shfl_xor(acc, 1, 4);
        acc += __shfl_xor(acc, 2, 4);
        if (l4 == 0) a0s[row] = acc;
    }
    __syncthreads();                                   // B3

    // ---- x1^T build: x1tg[j][k] = bf16(relu(a0[k]*w1[j]+b1[j])) ----
    {
        const int jj = tid >> 4, kk = (tid & 15) << 3;
        const float w1j = W1[jj], b1j = b1[jj];
        const fl4 av0 = *(const fl4*)&a0s[kk];
        const fl4 av1 = *(const fl4*)&a0s[kk + 4];
        union { unsigned u[4]; s8 v; } P;
        #pragma unroll
        for (int h = 0; h < 4; ++h) {
            const float e0 = (h < 2) ? av0[2 * h]     : av1[2 * h - 4];
            const float e1 = (h < 2) ? av0[2 * h + 1] : av1[2 * h - 3];
            const float x0 = fmaxf(fmaf(e0, w1j, b1j), 0.f);
            const float x1 = fmaxf(fmaf(e1, w1j, b1j), 0.f);
            P.u[h] = (unsigned)f2bf(x0) | ((unsigned)f2bf(x1) << 16);
        }
        *(s8*)&x1tg[(size_t)blockIdx.x * 4096 + jj * 128 + kk] = P.v;
    }
}

// ---------------------------------------------------------------------------
// Main kernel B: dense MFMA chain, ONE barrier. Per-wave-owned A^ rows:
// zero + scatter + A-frag reads + a1 writes + P7 reads are all same-wave
// (DS program order). B-frags (x1^T) and W2 frags read from global (L2-hot).
// LDS 35,328 B -> 4 blocks/CU.
// ---------------------------------------------------------------------------
__global__ __launch_bounds__(512, 6) void gcn_main_kernel(
    const unsigned* __restrict__ pslot_g,
    const short*    __restrict__ w2tg,
    const float*    __restrict__ nvg,
    const short*    __restrict__ x1tg,
    const float* __restrict__ b2, const float* __restrict__ W3,
    const float* __restrict__ b3,
    float* __restrict__ out)
{
    __shared__ __align__(16) short Ab[NUMK * ASTRIDE];  // 34816 B
    __shared__ float sbuf[NUMK];                        //   512 B

    const int tid = threadIdx.x;                // 0..511
    const int row = tid >> 2, l4 = tid & 3;     // 128 rows x 4 lanes
    const int wv = tid >> 6, lane = tid & 63;
    const int l = lane & 15, q = lane >> 4;
    const size_t g = blockIdx.x;

    // ---- per-thread loads (coalesced; nvg/x1tg L3-hot from prep) ----
    unsigned su[6]; float nvv[6];
    #pragma unroll
    for (int e = 0; e < 6; ++e) su[e] = pslot_g[(e << 9) + tid];
    #pragma unroll
    for (int e = 0; e < 6; ++e) nvv[e] = nvg[g * NPS + (e << 9) + tid];

    // ---- zero own-wave A^ rows, then scatter own row (same wave: in-order) ----
    {
        short* wbase = &Ab[(wv << 4) * ASTRIDE];
        for (int i = lane; i < (16 * ASTRIDE) / 8; i += 64)
            *(s8*)&wbase[i * 8] = (s8)0;
        #pragma unroll
        for (int e = 0; e < 6; ++e)
            if (su[e] >> 29)
                Ab[row * ASTRIDE + (int)(su[e] & 127u)] = (short)f2bf(nvv[e]);
    }

    // ---- a1 = A^ @ x1: A-frags own-wave LDS rows; B-frags global x1^T ----
    f4 acc0 = {0.f,0.f,0.f,0.f}, acc1 = {0.f,0.f,0.f,0.f};
    {
        const int arow = (wv << 4) + l;
        const short* xr0 = x1tg + g * 4096 + l * 128;
        const short* xr1 = x1tg + g * 4096 + (16 + l) * 128;
        #pragma unroll
        for (int ks = 0; ks < 4; ++ks) {
            const int kb = (ks << 5) + (q << 3);
            const s8 A  = *(const s8*)&Ab[arow * ASTRIDE + kb];
            const s8 B0 = *(const s8*)&xr0[kb];
            const s8 B1 = *(const s8*)&xr1[kb];
            acc0 = __builtin_amdgcn_mfma_f32_16x16x32_bf16(A, B0, acc0, 0, 0, 0);
            acc1 = __builtin_amdgcn_mfma_f32_16x16x32_bf16(A, B1, acc1, 0, 0, 0);
        }
    }

    // ---- a1 -> own A^ rows; P7: x2 = relu(a1@W2+b2), s = x2@W3 (same wave) ----
    {
        short* a1w = &Ab[(wv << 4) * ASTRIDE];
        #pragma unroll
        for (int r = 0; r < 4; ++r) {
            const int tr = (q << 2) + r;
            a1w[tr * W2STRIDE + l]      = (short)f2bf(acc0[r]);
            a1w[tr * W2STRIDE + 16 + l] = (short)f2bf(acc1[r]);
        }
        const s8 A0  = *(const s8*)&a1w[l * W2STRIDE + (q << 3)];
        const s8 Bw0 = *(const s8*)&w2tg[l * W2STRIDE + (q << 3)];
        const s8 Bw1 = *(const s8*)&w2tg[(16 + l) * W2STRIDE + (q << 3)];
        f4 ac20 = {0.f,0.f,0.f,0.f}, ac21 = {0.f,0.f,0.f,0.f};
        ac20 = __builtin_amdgcn_mfma_f32_16x16x32_bf16(A0, Bw0, ac20, 0, 0, 0);
        ac21 = __builtin_amdgcn_mfma_f32_16x16x32_bf16(A0, Bw1, ac21, 0, 0, 0);

        const float b2a = b2[l], b2b = b2[l + 16];
        const float w3a = W3[l], w3b = W3[l + 16];
        #pragma unroll
        for (int r = 0; r < 4; ++r) {
            const float v0 = fmaxf(ac20[r] + b2a, 0.f);
            const float v1 = fmaxf(ac21[r] + b2b, 0.f);
            float sv = v0 * w3a + v1 * w3b;
            #pragma unroll
            for (int m = 1; m < 16; m <<= 1) sv += __shfl_xor(sv, m, 16);
            if (l == 0) sbuf[(wv << 4) + (q << 2) + r] = sv;
        }
    }
    __syncthreads();                                   // the ONLY barrier

    // ---- P8: out = A^·s ----
    {
        float acc8 = 0.f;
        #pragma unroll
        for (int e = 0; e < 6; ++e)
            acc8 = fmaf(nvv[e], sbuf[su[e] & 127u], acc8);
        acc8 += __shfl_xor(acc8, 1, 4);
        acc8 += __shfl_xor(acc8, 2, 4);
        if (l4 == 0) out[g * NUMK + row] = acc8 + b3[0];
    }
}

extern "C" void kernel_launch(void* const* d_in, const int* in_sizes, int n_in,
                              void* d_out, int out_size, void* d_ws, size_t ws_size,
                              hipStream_t stream) {
    const float* Hx = (const float*)d_in[0];
    const int*   ei = (const int*)d_in[1];
    const float* W1 = (const float*)d_in[2];
    const float* b1 = (const float*)d_in[3];
    const float* W2 = (const float*)d_in[4];
    const float* b2 = (const float*)d_in[5];
    const float* W3 = (const float*)d_in[6];
    const float* b3 = (const float*)d_in[7];
    float* out = (float*)d_out;

    unsigned char* ws = (unsigned char*)d_ws;
    unsigned* pslot = (unsigned*)ws;                   // [3072]      12288 B
    short*    w2tg  = (short*)(ws + 12288);            // [1280]       2560 B
    unsigned* vmeta = (unsigned*)(ws + 14848);         // [17]
    float*    nvg   = (float*)(ws + 15360);            // 2048*3072 fp32 = 25.2 MB
    short*    x1tg  = (short*)(ws + 15360 + (size_t)NB * NPS * 4);  // 16.8 MB

    build_csr_kernel<<<1, 1024, 0, stream>>>(ei, W2, pslot, w2tg, vmeta);
    gcn_prep_kernel<<<NB, 512, 0, stream>>>(Hx, W1, b1, pslot, vmeta, nvg, x1tg);
    gcn_main_kernel<<<NB, 512, 0, stream>>>(pslot, w2tg, nvg, x1tg,
                                            b2, W3, b3, out);
}

// Round 14
// 101.970 us; speedup vs baseline: 1.1650x; 1.1650x over previous
//
#include <hip/hip_runtime.h>
#include <hip/hip_bf16.h>

#define NB    2048
#define NUMK  128
#define NE    1024
#define HID   32
#define ROWLEN (NUMK + NE + 2)
#define CAP   24                 // padded slots per row (unique srcs + self)
#define NPS   (NUMK * CAP)       // 3072
#define ASTRIDE 136              // bf16 elems per Â row (128 + 8 pad)
#define X1STRIDE 72              // bf16 elems per x1T-half row (64 + 8 pad)
#define W2STRIDE 40              // bf16 elems per a1/W2T row (32 + 8 pad)
#define WSELF 1024               // widx of self-loop weight (1.0)
#define WPAD  1025               // widx of pad weight (0.0)
#define WVBASE 1026              // first vslot (chained dup merges)
#define MAXV  16

// slot encoding: src(7) | widx(11)<<7 | widx2(11)<<18 | prim(1)<<29
// pslot layout (coalesced, 4 lanes/row x 6 slots):
//   pslot_g[e*512 + row*4 + l4] = psl[row][l4*6 + e],  e in [0,6)
// vmeta[1+v] = a(11) | b(11)<<11 : vslot weight = w(a) + w(b); a may chain to
//   an earlier vslot (linear chain), b is always a raw eid / WSELF.
// Weights/signals are read DIRECTLY from the graph's Hx row (L1-hot, 4.6 KB).

using s8  = __attribute__((ext_vector_type(8))) short;   // 8 bf16 = 16 B
using s4v = __attribute__((ext_vector_type(4))) short;   // 4 bf16 = 8 B
using f4  = __attribute__((ext_vector_type(4))) float;
using fl4 = __attribute__((ext_vector_type(4))) float;

static __device__ __forceinline__ unsigned short f2bf(float f) {
    unsigned u = __float_as_uint(f);
    unsigned r = (u + 0x7fffu + ((u >> 16) & 1u)) >> 16;   // RNE
    return (unsigned short)r;
}

// resolve a weight index (raw eid / WSELF / WPAD / vslot chain) from global
static __device__ __forceinline__ float wload(const float* __restrict__ rowp,
                                              unsigned idx,
                                              const unsigned* __restrict__ vmeta) {
    float w = 0.f;
    while (idx >= (unsigned)WVBASE) {                  // rare: >=3-dup chains
        const unsigned e = vmeta[1 + (idx - (unsigned)WVBASE)];
        const unsigned b = e >> 11;
        w += (b < 1024u) ? rowp[NUMK + b] : (b == (unsigned)WSELF ? 1.0f : 0.0f);
        idx = e & 0x7FFu;
    }
    w += (idx < 1024u) ? rowp[NUMK + idx] : (idx == (unsigned)WSELF ? 1.0f : 0.0f);
    return w;
}

// ---------------------------------------------------------------------------
// Setup (once): CSR by dst, per-row dedup into (widx, widx2 [, vslot chain]);
// pre-pack W2^T bf16 B-frag layout into ws. (Validated R12 code.)
// ---------------------------------------------------------------------------
__global__ __launch_bounds__(1024) void build_csr_kernel(
    const int* __restrict__ ei,
    const float* __restrict__ W2,
    unsigned* __restrict__ pslot_g,    // [NPS]
    short* __restrict__ w2tg,          // [HID * W2STRIDE]
    unsigned* __restrict__ vmeta_g)    // [1 + MAXV]
{
    __shared__ unsigned cnt[NUMK], roff[NUMK + 1], cur[NUMK], incl[NUMK];
    __shared__ unsigned pk[NE];
    __shared__ unsigned psl[NUMK][CAP];
    __shared__ unsigned vc;
    const int t = threadIdx.x;

    if (t < NUMK) cnt[t] = 0u;
    if (t == 0) vc = 0u;
    {   // W2^T bf16 pack: w2tg[n*40+k] = bf16(W2[k*32+n])
        const int k = t >> 5, n = t & 31;
        w2tg[n * W2STRIDE + k] = (short)f2bf(W2[t]);
    }
    __syncthreads();
    const int dst = ei[NE + t] & (NUMK - 1);
    atomicAdd(&cnt[dst], 1u);
    __syncthreads();

    if (t < NUMK) {                              // exclusive scan (2 wave scans)
        unsigned v = cnt[t];
        #pragma unroll
        for (int d = 1; d < 64; d <<= 1) {
            unsigned u = __shfl_up(v, d, 64);
            if ((t & 63) >= d) v += u;
        }
        incl[t] = v;
    }
    __syncthreads();
    if (t < NUMK) {
        const unsigned base = (t >= 64) ? incl[63] : 0u;
        const unsigned off  = base + incl[t] - cnt[t];
        roff[t] = off; cur[t] = off;
    }
    if (t == 0) roff[NUMK] = (unsigned)NE;
    __syncthreads();

    {
        const int src = ei[t] & (NUMK - 1);
        const unsigned pos = atomicAdd(&cur[dst], 1u);
        pk[pos] = (unsigned)src | ((unsigned)t << 16);
    }
    __syncthreads();

    if (t < NUMK) {
        int np = 0;
        auto addOrMerge = [&](unsigned s, unsigned eid) {
            int j = -1;
            for (int i = 0; i < np; ++i)
                if ((psl[t][i] & 127u) == s) { j = i; break; }
            if (j >= 0) {
                const unsigned slot = psl[t][j];
                const unsigned w2x = (slot >> 18) & 0x7FFu;
                if (w2x == (unsigned)WPAD) {
                    psl[t][j] = (slot & ~(0x7FFu << 18)) | (eid << 18);
                } else {
                    const unsigned v = atomicAdd(&vc, 1u);
                    if (v < (unsigned)MAXV) {
                        vmeta_g[1 + v] = w2x | (eid << 11);
                        psl[t][j] = (slot & ~(0x7FFu << 18))
                                  | (((unsigned)WVBASE + v) << 18);
                    }
                }
            } else if (np < CAP) {
                psl[t][np++] = s | (eid << 7)
                             | ((unsigned)WPAD << 18) | (1u << 29);
            }
        };
        const unsigned k0 = roff[t], k1 = roff[t + 1];
        for (unsigned k = k0; k < k1; ++k)
            addOrMerge(pk[k] & 127u, pk[k] >> 16);
        addOrMerge((unsigned)t, (unsigned)WSELF);        // self-loop, w = 1
        for (int i = np; i < CAP; ++i)                   // pads: w = 0, prim = 0
            psl[t][i] = ((unsigned)WPAD << 7) | ((unsigned)WPAD << 18);
    }
    __syncthreads();

    for (int i = t; i < NPS; i += 1024) {
        const int e = i >> 9, rem = i & 511;
        const int r = rem >> 2, l4i = rem & 3;
        pslot_g[i] = psl[r][l4i * 6 + e];
    }
    if (t == 0) vmeta_g[0] = (vc <= (unsigned)MAXV) ? vc : (unsigned)MAXV;
}

// ---------------------------------------------------------------------------
// Main: one block (512 thr = 8 waves) per graph; 40,448 B LDS -> 4 blocks/CU
// (thread-capped at 4 anyway). No LDS staging phase: weights/signals read
// straight from the L1-hot Hx row; vslot chains resolved in registers.
// 6 barriers. MFMA section verbatim from validated R11/R12.
// ---------------------------------------------------------------------------
__global__ __launch_bounds__(512, 6) void gcn_main_kernel(
    const float* __restrict__ Hx,
    const float* __restrict__ W1, const float* __restrict__ b1,
    const float* __restrict__ b2, const float* __restrict__ W3,
    const float* __restrict__ b3,
    const unsigned* __restrict__ pslot_g,
    const short*    __restrict__ w2tg,
    const unsigned* __restrict__ vmeta_g,
    float* __restrict__ out)
{
    __shared__ __align__(16) short Ab[NUMK * ASTRIDE];    // 34816 B
    __shared__ __align__(16) short x1h[HID * X1STRIDE];   //  4608 B
    __shared__ float degv[NUMK];                          //   512 B (dinv->sbuf)
    __shared__ float a0s[NUMK];                           //   512 B
    // total 40,448 B

    const int tid = threadIdx.x;                // 0..511
    const int row = tid >> 2, l4 = tid & 3;     // 128 rows x 4 lanes
    const int wv = tid >> 6, lane = tid & 63;
    const int l = lane & 15, q = lane >> 4;
    const float* rowp = Hx + (size_t)blockIdx.x * ROWLEN;

    // ---- slot loads + zero A^ (independent; overlap) ----
    unsigned su[6];
    #pragma unroll
    for (int e = 0; e < 6; ++e) su[e] = pslot_g[(e << 9) + tid];
    for (int t2 = tid; t2 < (NUMK * ASTRIDE) / 8; t2 += 512)
        *(s8*)&Ab[t2 * 8] = (s8)0;

    // ---- P2: merged slot weights from GLOBAL + deg -> dinv ----
    float nvr[6];
    {
        float d = 0.f;
        #pragma unroll
        for (int e = 0; e < 6; ++e) {
            const unsigned u = su[e];
            nvr[e] = wload(rowp, (u >> 7) & 0x7FFu, vmeta_g)
                   + wload(rowp, (u >> 18) & 0x7FFu, vmeta_g);
            d += nvr[e];
        }
        d += __shfl_xor(d, 1, 4);
        d += __shfl_xor(d, 2, 4);
        if (l4 == 0) degv[row] = rsqrtf(d);            // deg >= 1 (self w=1)
    }
    __syncthreads();                                   // B1

    // ---- P4: norms + A^ scatter (own row) + a0 = A^·p (p from global) ----
    {
        const float dr = degv[row];
        float acc = 0.f;
        #pragma unroll
        for (int e = 0; e < 6; ++e) {
            const unsigned u = su[e];
            const int s = (int)(u & 127u);
            const float nv = (u >> 29) ? dr * degv[s] * nvr[e] : 0.f;
            if (u >> 29) Ab[row * ASTRIDE + s] = (short)f2bf(nv);
            nvr[e] = nv;
            acc = fmaf(nv, rowp[s], acc);              // p[s] from L1-hot row
        }
        acc += __shfl_xor(acc, 1, 4);
        acc += __shfl_xor(acc, 2, 4);
        if (l4 == 0) a0s[row] = acc;
    }
    __syncthreads();                                   // B2

    // ---- layer-2 propagate: a1 = A^ @ x1, x1 built in two 64-K halves ----
    f4 accm0 = {0.f,0.f,0.f,0.f}, accm1 = {0.f,0.f,0.f,0.f};
    const int arow = (wv << 4) + l;                    // wave-exclusive A^ row
    #pragma unroll
    for (int half = 0; half < 2; ++half) {
        {   // build x1h half: x1h[j][k] = relu(a0[64h+k]*w1[j]+b1[j])
            const int jj = tid >> 4;                   // x1T row 0..31
            const float w1j = W1[jj], b1j = b1[jj];    // L2-hot
            const int kk = (tid & 15) << 2;            // 0..60
            const fl4 av = *(const fl4*)&a0s[(half << 6) + kk];
            union { unsigned u[2]; s4v v; } P;
            P.u[0] = (unsigned)f2bf(fmaxf(fmaf(av[0], w1j, b1j), 0.f))
                   | ((unsigned)f2bf(fmaxf(fmaf(av[1], w1j, b1j), 0.f)) << 16);
            P.u[1] = (unsigned)f2bf(fmaxf(fmaf(av[2], w1j, b1j), 0.f))
                   | ((unsigned)f2bf(fmaxf(fmaf(av[3], w1j, b1j), 0.f)) << 16);
            *(s4v*)&x1h[jj * X1STRIDE + kk] = P.v;
        }
        __syncthreads();                               // B3 / B5
        #pragma unroll
        for (int ks2 = 0; ks2 < 2; ++ks2) {
            const int kloc = (ks2 << 5) + (q << 3);
            const s8 A  = *(const s8*)&Ab[arow * ASTRIDE + (half << 6) + kloc];
            const s8 B0 = *(const s8*)&x1h[l * X1STRIDE + kloc];
            const s8 B1 = *(const s8*)&x1h[(16 + l) * X1STRIDE + kloc];
            accm0 = __builtin_amdgcn_mfma_f32_16x16x32_bf16(A, B0, accm0, 0, 0, 0);
            accm1 = __builtin_amdgcn_mfma_f32_16x16x32_bf16(A, B1, accm1, 0, 0, 0);
        }
        if (half == 0) __syncthreads();                // B4 (x1h reads done)
    }

    // ---- a1 -> own A^ rows (same wave, DS in-order: no barrier) ----
    short* a1w = &Ab[(wv << 4) * ASTRIDE];             // 16 rows x W2STRIDE
    #pragma unroll
    for (int r = 0; r < 4; ++r) {
        const int tr = (q << 2) + r;
        a1w[tr * W2STRIDE + l]      = (short)f2bf(accm0[r]);
        a1w[tr * W2STRIDE + 16 + l] = (short)f2bf(accm1[r]);
    }

    // ---- P7: x2 = relu(a1@W2+b2); s = x2@W3 (same-wave; W2 frags global) ----
    {
        const s8 A0  = *(const s8*)&a1w[l * W2STRIDE + (q << 3)];
        const s8 Bw0 = *(const s8*)&w2tg[l * W2STRIDE + (q << 3)];
        const s8 Bw1 = *(const s8*)&w2tg[(16 + l) * W2STRIDE + (q << 3)];
        f4 ac20 = {0.f,0.f,0.f,0.f}, ac21 = {0.f,0.f,0.f,0.f};
        ac20 = __builtin_amdgcn_mfma_f32_16x16x32_bf16(A0, Bw0, ac20, 0, 0, 0);
        ac21 = __builtin_amdgcn_mfma_f32_16x16x32_bf16(A0, Bw1, ac21, 0, 0, 0);

        const float b2a = b2[l], b2b = b2[l + 16];     // L2-hot, loaded at use
        const float w3a = W3[l], w3b = W3[l + 16];
        float* sbuf = degv;                            // dinv dead after P4
        #pragma unroll
        for (int r = 0; r < 4; ++r) {
            const float v0 = fmaxf(ac20[r] + b2a, 0.f);
            const float v1 = fmaxf(ac21[r] + b2b, 0.f);
            float sv = v0 * w3a + v1 * w3b;
            #pragma unroll
            for (int m = 1; m < 16; m <<= 1) sv += __shfl_xor(sv, m, 16);
            if (l == 0) sbuf[(wv << 4) + (q << 2) + r] = sv;
        }
    }
    __syncthreads();                                   // B6

    // ---- P8: out = A^·s (norms + slots from regs) ----
    {
        float* sbuf = degv;
        float acc8 = 0.f;
        #pragma unroll
        for (int e = 0; e < 6; ++e)
            acc8 = fmaf(nvr[e], sbuf[su[e] & 127u], acc8);
        acc8 += __shfl_xor(acc8, 1, 4);
        acc8 += __shfl_xor(acc8, 2, 4);
        if (l4 == 0) out[(size_t)blockIdx.x * NUMK + row] = acc8 + b3[0];
    }
}

extern "C" void kernel_launch(void* const* d_in, const int* in_sizes, int n_in,
                              void* d_out, int out_size, void* d_ws, size_t ws_size,
                              hipStream_t stream) {
    const float* Hx = (const float*)d_in[0];
    const int*   ei = (const int*)d_in[1];
    const float* W1 = (const float*)d_in[2];
    const float* b1 = (const float*)d_in[3];
    const float* W2 = (const float*)d_in[4];
    const float* b2 = (const float*)d_in[5];
    const float* W3 = (const float*)d_in[6];
    const float* b3 = (const float*)d_in[7];
    float* out = (float*)d_out;

    unsigned* pslot = (unsigned*)d_ws;                 // [3072]   12288 B
    short*    w2tg  = (short*)(pslot + NPS);           // [1280]    2560 B
    unsigned* vmeta = (unsigned*)(w2tg + HID * W2STRIDE); // [1+MAXV]

    build_csr_kernel<<<1, 1024, 0, stream>>>(ei, W2, pslot, w2tg, vmeta);
    gcn_main_kernel<<<NB, 512, 0, stream>>>(Hx, W1, b1, b2, W3, b3,
                                            pslot, w2tg, vmeta, out);
}